// Round 18
// baseline (6008.400 us; speedup 1.0000x reference)
//
#include <hip/hip_runtime.h>

#define Tn 512
#define Hn 512
#define HS 65536           // u32 elements per h ring slot (128*512)
#define NBLK 256

typedef __attribute__((ext_vector_type(8))) short s8v;     // 8 bf16 (MFMA A/B frag)
typedef __attribute__((ext_vector_type(4))) float f4v;     // MFMA acc
typedef __attribute__((ext_vector_type(4))) unsigned u4v;
typedef unsigned long long ull;

__device__ __forceinline__ unsigned short f2bf(float f) {  // RNE
  unsigned u = __float_as_uint(f);
  u = u + 0x7fffu + ((u >> 16) & 1u);
  return (unsigned short)(u >> 16);
}
__device__ __forceinline__ float bf2f(unsigned short s) {
  return __uint_as_float(((unsigned)s) << 16);
}
__device__ __forceinline__ float sigm(float v) { return 1.f / (1.f + __expf(-v)); }
__device__ __forceinline__ float tanh_f(float v) {
  v = fminf(fmaxf(v, -15.f), 15.f);
  float e = __expf(2.f * v);
  return (e - 1.f) / (e + 1.f);
}
__device__ __forceinline__ f4v mfma3(s8v ah, s8v al, s8v whh, s8v wll, f4v c) {
  c = __builtin_amdgcn_mfma_f32_16x16x32_bf16(ah, whh, c, 0, 0, 0);
  c = __builtin_amdgcn_mfma_f32_16x16x32_bf16(al, whh, c, 0, 0, 0);
  c = __builtin_amdgcn_mfma_f32_16x16x32_bf16(ah, wll, c, 0, 0, 0);
  return c;
}

// MALL-coherent (agent-scope, relaxed) accessors -> sc1 ops, no cache maintenance.
__device__ __forceinline__ ull ld_mall64(const ull* p) {
  return __hip_atomic_load(p, __ATOMIC_RELAXED, __HIP_MEMORY_SCOPE_AGENT);
}
__device__ __forceinline__ void st_mall(unsigned* p, unsigned v) {
  __hip_atomic_store(p, v, __ATOMIC_RELAXED, __HIP_MEMORY_SCOPE_AGENT);
}

// Dual-line flag poll: lanes 0..31 check lineA[lane] >= ta, lanes 32..63 check
// lineB[lane-32] >= tb.
__device__ __forceinline__ void poll2(const int* pa, int ta, const int* pb2, int tb,
                                      int lane) {
  const int* p = (lane < 32) ? (pa + lane) : (pb2 + (lane - 32));
  const int tgt = (lane < 32) ? ta : tb;
  for (;;) {
    int v = (int)__hip_atomic_load(p, __ATOMIC_RELAXED, __HIP_MEMORY_SCOPE_AGENT);
    if (__all(v >= tgt)) break;
    __builtin_amdgcn_s_sleep(1);
  }
  asm volatile("" ::: "memory");   // no data loads hoisted above the poll
}

// ---------------- persistent fused 2-layer GRU (round-17 structure) ----------------
// 256 blocks x 512 threads. g = bid&7 = mq*2+layer; jg = bid>>3 (16 cols).
// Waves 0-3: input side, K/4 each (x regs for l0 / h1[t] ring for l1).
// Waves 4-7: h side, K/4 each. Waves 4/5 are combiners for mt 0/1.
// Weight hi frags VGPR (48/wave); weight LO frags LDS (12 KB/wave).
// h GEMM: two sequential 16x8B batches (r17, reg-budget-resident).
// CHANGE vs r17 (the only one): arrival is STORE-ONLY -- no atomic RMW.
// comb1 drains its h stores then writes a monotonic LDS token (t+1); comb0
// drains, spins on the token (in-CU, ~100ns), then STORES flags[g][jg]=t+1.
// This removes 64 same-line MALL RMWs per group per step (the r5 lesson,
// quietly reintroduced by r10's fetch_add arrival). Poll targets revert to
// t-scale. Release ordering: both drains precede token/flag; flag store is
// program-ordered after the token observation. Liveness is block-local.
__global__ void __launch_bounds__(512) __attribute__((amdgpu_waves_per_eu(2, 2)))
gru_fused(
    const float* __restrict__ x,
    const float* __restrict__ Wih0, const float* __restrict__ Whh0,
    const float* __restrict__ bih0, const float* __restrict__ bhh0,
    const float* __restrict__ Wih1, const float* __restrict__ Whh1,
    const float* __restrict__ bih1, const float* __restrict__ bhh1,
    int* __restrict__ flags,       // [8][32] int, = t+1 after step t
    unsigned* __restrict__ h1ring, // 4 slots x 65536 u32
    unsigned* __restrict__ h2ring, // 2 slots x 65536 u32
    float* __restrict__ h2fin) {
  // LDS: part[8][64][28] floats (57344 B) + 8 x 12288 B weight-lo + token
  __shared__ __align__(16) float smem[38928];          // 155712 B total
  float (*part)[64][28] = (float (*)[64][28])smem;
  volatile int* const token = (volatile int*)&smem[38912];

  const int tid = threadIdx.x, lane = tid & 63, wv = tid >> 6;
  const bool inside = (wv < 4);          // input-side wave
  const int kq = wv & 3;                 // K/4 slice (128 k)
  const bool comb0 = (wv == 4), comb1 = (wv == 5);
  const int colr = lane & 15, kg = lane >> 4;

  const int bid = blockIdx.x;
  const int g = bid & 7;
  const int layer = g & 1;
  const int mq = g >> 1;                 // row quarter (32 rows)
  const int jg = bid >> 3;               // 0..31 column group
  const int col = jg * 16 + colr;

  s8v* const wlf = (s8v*)((char*)smem + 57344 + wv * 12288);  // this wave's lo frags

  if (tid == 0) *token = 0;

  // ---- weights: hi -> VGPR, lo -> LDS.  k = kq*128 + ks*32 + kg*8 + e ----
  const float* W = inside ? (layer ? Wih1 : Wih0) : (layer ? Whh1 : Whh0);
  s8v wh[3][4];
#pragma unroll
  for (int gg = 0; gg < 3; ++gg) {
    const float* wrow = W + (size_t)(gg * Hn + col) * Hn + kq * 128 + kg * 8;
#pragma unroll
    for (int ks = 0; ks < 4; ++ks) {
      s8v lov;
#pragma unroll
      for (int e = 0; e < 8; ++e) {
        float v = wrow[ks * 32 + e];
        unsigned short hi = f2bf(v);
        wh[gg][ks][e] = (short)hi;
        lov[e] = (short)f2bf(v - bf2f(hi));
      }
      wlf[(gg * 4 + ks) * 64 + lane] = lov;
    }
  }

  // biases: combiner waves only
  float brz = 0, bzz = 0, bin = 0, bhn = 0;
  if (comb0 || comb1) {
    const float* bi = layer ? bih1 : bih0;
    const float* bb = layer ? bhh1 : bhh0;
    brz = bi[col] + bb[col];
    bzz = bi[Hn + col] + bb[Hn + col];
    bin = bi[2 * Hn + col];
    bhn = bb[2 * Hn + col];
  }

  const bool is_xw = (layer == 0 && inside);

  float4 xp[2][4][2];   // x prefetch: 2 mt x 4 ks x 2 float4 = 64 VGPR
  if (is_xw) {
#pragma unroll
    for (int mt = 0; mt < 2; ++mt) {
      const int rowA = mq * 32 + mt * 16 + colr;
      const float* xq = x + ((size_t)rowA * Tn) * 512 + kq * 128 + kg * 8;  // t=0
#pragma unroll
      for (int ks = 0; ks < 4; ++ks) {
        xp[mt][ks][0] = *(const float4*)(xq + ks * 32);
        xp[mt][ks][1] = *(const float4*)(xq + ks * 32 + 4);
      }
    }
  }

  int* const ownline = flags + g * 32;
  int* const l0line = flags + (mq * 2) * 32;
  int* const l1line = flags + (mq * 2 + 1) * 32;

  float hown[4] = {0.f, 0.f, 0.f, 0.f};   // combiner's h slice (its mt, 16 rows)

  __syncthreads();

#pragma unroll 1
  for (int t = 0; t < Tn; ++t) {
    // ---- ordering polls (flags ARE the barrier; store-only, t-scale) ----
    if (layer == 0) {
      if (comb0 || comb1) poll2(ownline, t, l1line, t - 3, lane);
      else if (!inside)   poll2(ownline, t, ownline, t, lane);
    } else {
      if (inside) poll2(l0line, t + 1, l0line, t + 1, lane);
      else        poll2(ownline, t, ownline, t, lane);
    }
    __syncthreads();   // barrier #1: part free (combiners done reading prev step)

    f4v acc[2][3];
#pragma unroll
    for (int mt = 0; mt < 2; ++mt)
#pragma unroll
      for (int gg = 0; gg < 3; ++gg) acc[mt][gg] = (f4v){0.f, 0.f, 0.f, 0.f};

    if (is_xw) {
      // ---- x GEMM from prefetched regs; hi/lo by truncation; wl from LDS ----
#pragma unroll
      for (int ks = 0; ks < 4; ++ks) {
        s8v wl0 = wlf[(0 * 4 + ks) * 64 + lane];
        s8v wl1 = wlf[(1 * 4 + ks) * 64 + lane];
        s8v wl2 = wlf[(2 * 4 + ks) * 64 + lane];
#pragma unroll
        for (int mt = 0; mt < 2; ++mt) {
          float v[8];
          v[0] = xp[mt][ks][0].x; v[1] = xp[mt][ks][0].y;
          v[2] = xp[mt][ks][0].z; v[3] = xp[mt][ks][0].w;
          v[4] = xp[mt][ks][1].x; v[5] = xp[mt][ks][1].y;
          v[6] = xp[mt][ks][1].z; v[7] = xp[mt][ks][1].w;
          u4v au, lu;
#pragma unroll
          for (int q = 0; q < 4; ++q) {
            unsigned u0 = __float_as_uint(v[2 * q]);
            unsigned u1 = __float_as_uint(v[2 * q + 1]);
            unsigned m0 = u0 & 0xffff0000u, m1 = u1 & 0xffff0000u;
            au[q] = (u0 >> 16) | m1;
            float l0 = v[2 * q] - __uint_as_float(m0);
            float l1 = v[2 * q + 1] - __uint_as_float(m1);
            lu[q] = (__float_as_uint(l0) >> 16) | (__float_as_uint(l1) & 0xffff0000u);
          }
          s8v ah = __builtin_bit_cast(s8v, au);
          s8v al = __builtin_bit_cast(s8v, lu);
          acc[mt][0] = mfma3(ah, al, wh[0][ks], wl0, acc[mt][0]);
          acc[mt][1] = mfma3(ah, al, wh[1][ks], wl1, acc[mt][1]);
          acc[mt][2] = mfma3(ah, al, wh[2][ks], wl2, acc[mt][2]);
        }
      }
      // part write (frees acc), then issue next-step x loads
#pragma unroll
      for (int mt = 0; mt < 2; ++mt)
#pragma unroll
        for (int gg = 0; gg < 3; ++gg)
          *(f4v*)&part[wv][lane][mt * 12 + gg * 4] = acc[mt][gg];
      const int tpre = (t + 1 < Tn) ? (t + 1) : (Tn - 1);
#pragma unroll
      for (int mt = 0; mt < 2; ++mt) {
        const int rowA = mq * 32 + mt * 16 + colr;
        const float* xq = x + ((size_t)rowA * Tn + tpre) * 512 + kq * 128 + kg * 8;
#pragma unroll
        for (int ks = 0; ks < 4; ++ks) {
          xp[mt][ks][0] = *(const float4*)(xq + ks * 32);
          xp[mt][ks][1] = *(const float4*)(xq + ks * 32 + 4);
        }
      }
    } else {
      // ---- h GEMM: two SEQUENTIAL 16x8B batches (each fits the reg budget) ----
      const unsigned* src;
      if (inside)      src = h1ring + (size_t)(t & 3) * HS;        // l1: h1[t]
      else if (layer)  src = h2ring + (size_t)((t - 1) & 1) * HS;  // l1 h: h2[t-1]
      else             src = h1ring + (size_t)((t - 1) & 3) * HS;  // l0 h: h1[t-1]

      // ---- m-tile 0 ----
      {
        const int rowA = mq * 32 + colr;
        const ull* pb64 = (const ull*)(src + (size_t)rowA * 512 + kq * 128 + kg * 8);
        ull ub[16];
#pragma unroll
        for (int i = 0; i < 16; ++i)
          ub[i] = ld_mall64(pb64 + (i >> 2) * 16 + (i & 3));
#pragma unroll
        for (int ks = 0; ks < 4; ++ks) {
          s8v wl0 = wlf[(0 * 4 + ks) * 64 + lane];
          s8v wl1 = wlf[(1 * 4 + ks) * 64 + lane];
          s8v wl2 = wlf[(2 * 4 + ks) * 64 + lane];
          u4v ahw, alw;
#pragma unroll
          for (int j = 0; j < 4; ++j) {
            unsigned a = (unsigned)ub[ks * 4 + j];
            unsigned b = (unsigned)(ub[ks * 4 + j] >> 32);
            ahw[j] = (a >> 16) | (b & 0xffff0000u);
            alw[j] = (a & 0xffffu) | (b << 16);
          }
          s8v AH = __builtin_bit_cast(s8v, ahw);
          s8v AL = __builtin_bit_cast(s8v, alw);
          acc[0][0] = mfma3(AH, AL, wh[0][ks], wl0, acc[0][0]);
          acc[0][1] = mfma3(AH, AL, wh[1][ks], wl1, acc[0][1]);
          acc[0][2] = mfma3(AH, AL, wh[2][ks], wl2, acc[0][2]);
        }
      }
      asm volatile("" ::: "memory");   // keep tile-1 loads from merging into tile 0
      // ---- m-tile 1 ----
      {
        const int rowA = mq * 32 + 16 + colr;
        const ull* pb64 = (const ull*)(src + (size_t)rowA * 512 + kq * 128 + kg * 8);
        ull ub[16];
#pragma unroll
        for (int i = 0; i < 16; ++i)
          ub[i] = ld_mall64(pb64 + (i >> 2) * 16 + (i & 3));
#pragma unroll
        for (int ks = 0; ks < 4; ++ks) {
          s8v wl0 = wlf[(0 * 4 + ks) * 64 + lane];
          s8v wl1 = wlf[(1 * 4 + ks) * 64 + lane];
          s8v wl2 = wlf[(2 * 4 + ks) * 64 + lane];
          u4v ahw, alw;
#pragma unroll
          for (int j = 0; j < 4; ++j) {
            unsigned a = (unsigned)ub[ks * 4 + j];
            unsigned b = (unsigned)(ub[ks * 4 + j] >> 32);
            ahw[j] = (a >> 16) | (b & 0xffff0000u);
            alw[j] = (a & 0xffffu) | (b << 16);
          }
          s8v AH = __builtin_bit_cast(s8v, ahw);
          s8v AL = __builtin_bit_cast(s8v, alw);
          acc[1][0] = mfma3(AH, AL, wh[0][ks], wl0, acc[1][0]);
          acc[1][1] = mfma3(AH, AL, wh[1][ks], wl1, acc[1][1]);
          acc[1][2] = mfma3(AH, AL, wh[2][ks], wl2, acc[1][2]);
        }
      }
      // part write: combiners stash only their OTHER mt; others both mt
      if (comb0) {
#pragma unroll
        for (int gg = 0; gg < 3; ++gg)
          *(f4v*)&part[4][lane][gg * 4] = acc[1][gg];
      } else if (comb1) {
#pragma unroll
        for (int gg = 0; gg < 3; ++gg)
          *(f4v*)&part[5][lane][gg * 4] = acc[0][gg];
      } else {
#pragma unroll
        for (int mt = 0; mt < 2; ++mt)
#pragma unroll
          for (int gg = 0; gg < 3; ++gg)
            *(f4v*)&part[wv][lane][mt * 12 + gg * 4] = acc[mt][gg];
      }
    }
    __syncthreads();   // barrier #2: parts ready

    // ---- combiners (waves 4, 5 in parallel, one mt each) ----
    if (comb0 || comb1) {
      const int mt = comb0 ? 0 : 1;
      const int moff = mt * 12;
      f4v xs[3], hsum[3];
#pragma unroll
      for (int gg = 0; gg < 3; ++gg) {
        xs[gg] = *(const f4v*)&part[0][lane][moff + gg * 4]
               + *(const f4v*)&part[1][lane][moff + gg * 4]
               + *(const f4v*)&part[2][lane][moff + gg * 4]
               + *(const f4v*)&part[3][lane][moff + gg * 4];
        hsum[gg] = acc[mt][gg]
                 + *(const f4v*)&part[comb0 ? 5 : 4][lane][gg * 4]
                 + *(const f4v*)&part[6][lane][moff + gg * 4]
                 + *(const f4v*)&part[7][lane][moff + gg * 4];
      }
      unsigned* od = layer ? (h2ring + (size_t)(t & 1) * HS)
                           : (h1ring + (size_t)(t & 3) * HS);
#pragma unroll
      for (int r = 0; r < 4; ++r) {
        float rr = sigm(xs[0][r] + hsum[0][r] + brz);
        float zz = sigm(xs[1][r] + hsum[1][r] + bzz);
        float nn = tanh_f(xs[2][r] + bin + rr * (hsum[2][r] + bhn));
        float h = (1.f - zz) * nn + zz * hown[r];
        hown[r] = h;
        const int row = mq * 32 + mt * 16 + kg * 4 + r;
        unsigned short hi = f2bf(h);
        unsigned pk = ((unsigned)hi << 16) | (unsigned)f2bf(h - bf2f(hi));
        st_mall(od + (size_t)row * 512 + col, pk);
        if (layer == 1 && t == Tn - 1) h2fin[(size_t)row * 512 + col] = h;
      }
      // release: drain this wave's h stores; comb1 hands a token to comb0,
      // comb0 (after observing it) publishes the single per-block flag STORE.
      asm volatile("s_waitcnt vmcnt(0)" ::: "memory");
      if (comb1) {
        if (lane == 0) *token = t + 1;
      } else {
        while (*token < t + 1) { }
        asm volatile("" ::: "memory");
        if (lane == 0)
          st_mall((unsigned*)(ownline + jg), (unsigned)(t + 1));
      }
    }
  }
}

// ---------- epilogue: out = h2_last @ Wfc^T + bfc ----------
__global__ __launch_bounds__(256) void fc_kernel(const float* __restrict__ h2,
                                                 const float* __restrict__ Wfc,
                                                 const float* __restrict__ bfc,
                                                 float* __restrict__ out) {
  int gid = blockIdx.x * 256 + threadIdx.x;  // 0..16383
  int b = gid >> 7, o = gid & 127;
  const float* hp = h2 + (size_t)b * Hn;
  const float* wp = Wfc + (size_t)o * Hn;
  float acc = bfc[o];
#pragma unroll 8
  for (int k = 0; k < Hn; k += 4) {
    float4 h = *(const float4*)(hp + k);
    float4 w = *(const float4*)(wp + k);
    acc = fmaf(h.x, w.x, acc); acc = fmaf(h.y, w.y, acc);
    acc = fmaf(h.z, w.z, acc); acc = fmaf(h.w, w.w, acc);
  }
  out[gid] = acc;
}

// ---------- epilogue: out_cate = out @ Wfcc^T + bfcc ----------
__global__ __launch_bounds__(256) void fcc_kernel(const float* __restrict__ outv,
                                                  const float* __restrict__ Wfcc,
                                                  const float* __restrict__ bfcc,
                                                  float* __restrict__ oc) {
  int gid = blockIdx.x * 256 + threadIdx.x;  // 0..49151
  int b = gid / 384, g = gid - b * 384;
  const float* op = outv + (size_t)b * 128;
  const float* wp = Wfcc + (size_t)g * 128;
  float acc = bfcc[g];
#pragma unroll 8
  for (int k = 0; k < 128; k += 4) {
    float4 o4 = *(const float4*)(op + k);
    float4 w4 = *(const float4*)(wp + k);
    acc = fmaf(o4.x, w4.x, acc); acc = fmaf(o4.y, w4.y, acc);
    acc = fmaf(o4.z, w4.z, acc); acc = fmaf(o4.w, w4.w, acc);
  }
  oc[gid] = acc;
}

extern "C" void kernel_launch(void* const* d_in, const int* in_sizes, int n_in,
                              void* d_out, int out_size, void* d_ws, size_t ws_size,
                              hipStream_t stream) {
  (void)in_sizes; (void)n_in; (void)out_size; (void)ws_size;
  const float* x    = (const float*)d_in[0];
  const float* Wih0 = (const float*)d_in[1];
  const float* Whh0 = (const float*)d_in[2];
  const float* bih0 = (const float*)d_in[3];
  const float* bhh0 = (const float*)d_in[4];
  const float* Wih1 = (const float*)d_in[5];
  const float* Whh1 = (const float*)d_in[6];
  const float* bih1 = (const float*)d_in[7];
  const float* bhh1 = (const float*)d_in[8];
  const float* Wfc  = (const float*)d_in[9];
  const float* bfc  = (const float*)d_in[10];
  const float* Wfcc = (const float*)d_in[11];
  const float* bfcc = (const float*)d_in[12];

  char* w = (char*)d_ws;
  int* flags = (int*)w;                            // [8][32] int, 1 KB
  unsigned* h1ring = (unsigned*)(w + 8192);        // 4 * 65536 u32 = 1 MB
  unsigned* h2ring = h1ring + 4 * HS;              // 2 * 65536 u32 = 512 KB
  float* h2fin = (float*)(h2ring + 2 * HS);        // 256 KB
  const size_t total = 8192 + (size_t)4 * HS * 4 + (size_t)2 * HS * 4 + (size_t)HS * 4;

  hipMemsetAsync(d_ws, 0, total, stream);

  gru_fused<<<NBLK, 512, 0, stream>>>(x, Wih0, Whh0, bih0, bhh0,
                                      Wih1, Whh1, bih1, bhh1,
                                      flags, h1ring, h2ring, h2fin);

  float* out = (float*)d_out;
  fc_kernel<<<64, 256, 0, stream>>>(h2fin, Wfc, bfc, out);
  fcc_kernel<<<192, 256, 0, stream>>>(out, Wfcc, bfcc, out + 16384);
}

// Round 19
// 5116.742 us; speedup vs baseline: 1.1743x; 1.1743x over previous
//
#include <hip/hip_runtime.h>

#define Tn 512
#define Hn 512
#define HS 65536           // u32 elements per h ring slot (128*512)
#define NBLK 256

typedef __attribute__((ext_vector_type(8))) short s8v;     // 8 bf16 (MFMA A/B frag)
typedef __attribute__((ext_vector_type(4))) float f4v;     // MFMA acc
typedef __attribute__((ext_vector_type(4))) unsigned u4v;
typedef unsigned long long ull;

__device__ __forceinline__ unsigned short f2bf(float f) {  // RNE
  unsigned u = __float_as_uint(f);
  u = u + 0x7fffu + ((u >> 16) & 1u);
  return (unsigned short)(u >> 16);
}
__device__ __forceinline__ float bf2f(unsigned short s) {
  return __uint_as_float(((unsigned)s) << 16);
}
__device__ __forceinline__ float sigm(float v) { return 1.f / (1.f + __expf(-v)); }
__device__ __forceinline__ float tanh_f(float v) {
  v = fminf(fmaxf(v, -15.f), 15.f);
  float e = __expf(2.f * v);
  return (e - 1.f) / (e + 1.f);
}
__device__ __forceinline__ f4v mfma3(s8v ah, s8v al, s8v whh, s8v wll, f4v c) {
  c = __builtin_amdgcn_mfma_f32_16x16x32_bf16(ah, whh, c, 0, 0, 0);
  c = __builtin_amdgcn_mfma_f32_16x16x32_bf16(al, whh, c, 0, 0, 0);
  c = __builtin_amdgcn_mfma_f32_16x16x32_bf16(ah, wll, c, 0, 0, 0);
  return c;
}

// MALL-coherent (agent-scope, relaxed) accessors -> sc1 ops, no cache maintenance.
__device__ __forceinline__ ull ld_mall64(const ull* p) {
  return __hip_atomic_load(p, __ATOMIC_RELAXED, __HIP_MEMORY_SCOPE_AGENT);
}
__device__ __forceinline__ void st_mall(unsigned* p, unsigned v) {
  __hip_atomic_store(p, v, __ATOMIC_RELAXED, __HIP_MEMORY_SCOPE_AGENT);
}

// Dual-line flag poll: lanes 0..31 check lineA[lane] >= ta, lanes 32..63 check
// lineB[lane-32] >= tb.
__device__ __forceinline__ void poll2(const int* pa, int ta, const int* pb2, int tb,
                                      int lane) {
  const int* p = (lane < 32) ? (pa + lane) : (pb2 + (lane - 32));
  const int tgt = (lane < 32) ? ta : tb;
  for (;;) {
    int v = (int)__hip_atomic_load(p, __ATOMIC_RELAXED, __HIP_MEMORY_SCOPE_AGENT);
    if (__all(v >= tgt)) break;
    __builtin_amdgcn_s_sleep(1);
  }
  asm volatile("" ::: "memory");   // no data loads hoisted above the poll
}

// ---------------- persistent fused 2-layer GRU (round-17 = measured optimum) --------
// 256 blocks x 512 threads. g = bid&7 = mq*2+layer; jg = bid>>3 (16 cols).
// Waves 0-3: input side, K/4 each (x regs for l0 / h1[t] ring for l1).
// Waves 4-7: h side, K/4 each. Waves 4/5 are combiners for mt 0/1.
// Weight hi fragments in VGPRs (48/wave); weight LO fragments in LDS (12 KB/wave).
// h GEMM: two SEQUENTIAL 16x8B batches (each fits the 128-reg budget -> fully
// resident, one waitcnt each). Arrival: fetch_add x2/block/step (r10-proven).
// This configuration is the measured optimum of 18 protocol/load variants
// (5.17-5.21 ms); the per-step floor is cross-CU all-gather latency, not
// compute (MfmaUtil ~8.5%) or bandwidth (~1.2% HBM).
__global__ void __launch_bounds__(512) __attribute__((amdgpu_waves_per_eu(2, 2)))
gru_fused(
    const float* __restrict__ x,
    const float* __restrict__ Wih0, const float* __restrict__ Whh0,
    const float* __restrict__ bih0, const float* __restrict__ bhh0,
    const float* __restrict__ Wih1, const float* __restrict__ Whh1,
    const float* __restrict__ bih1, const float* __restrict__ bhh1,
    int* __restrict__ flags,       // [8][32] int, += 2 per block per step
    unsigned* __restrict__ h1ring, // 4 slots x 65536 u32
    unsigned* __restrict__ h2ring, // 2 slots x 65536 u32
    float* __restrict__ h2fin) {
  // LDS: part[8][64][28] floats (57344 B) + 8 x 12288 B weight-lo regions
  __shared__ __align__(16) float smem[38912];          // 155648 B total
  float (*part)[64][28] = (float (*)[64][28])smem;

  const int tid = threadIdx.x, lane = tid & 63, wv = tid >> 6;
  const bool inside = (wv < 4);          // input-side wave
  const int kq = wv & 3;                 // K/4 slice (128 k)
  const bool comb0 = (wv == 4), comb1 = (wv == 5);
  const int colr = lane & 15, kg = lane >> 4;

  const int bid = blockIdx.x;
  const int g = bid & 7;
  const int layer = g & 1;
  const int mq = g >> 1;                 // row quarter (32 rows)
  const int jg = bid >> 3;               // 0..31 column group
  const int col = jg * 16 + colr;

  s8v* const wlf = (s8v*)((char*)smem + 57344 + wv * 12288);  // this wave's lo frags

  // ---- weights: hi -> VGPR, lo -> LDS.  k = kq*128 + ks*32 + kg*8 + e ----
  const float* W = inside ? (layer ? Wih1 : Wih0) : (layer ? Whh1 : Whh0);
  s8v wh[3][4];
#pragma unroll
  for (int gg = 0; gg < 3; ++gg) {
    const float* wrow = W + (size_t)(gg * Hn + col) * Hn + kq * 128 + kg * 8;
#pragma unroll
    for (int ks = 0; ks < 4; ++ks) {
      s8v lov;
#pragma unroll
      for (int e = 0; e < 8; ++e) {
        float v = wrow[ks * 32 + e];
        unsigned short hi = f2bf(v);
        wh[gg][ks][e] = (short)hi;
        lov[e] = (short)f2bf(v - bf2f(hi));
      }
      wlf[(gg * 4 + ks) * 64 + lane] = lov;
    }
  }

  // biases: combiner waves only
  float brz = 0, bzz = 0, bin = 0, bhn = 0;
  if (comb0 || comb1) {
    const float* bi = layer ? bih1 : bih0;
    const float* bb = layer ? bhh1 : bhh0;
    brz = bi[col] + bb[col];
    bzz = bi[Hn + col] + bb[Hn + col];
    bin = bi[2 * Hn + col];
    bhn = bb[2 * Hn + col];
  }

  const bool is_xw = (layer == 0 && inside);

  float4 xp[2][4][2];   // x prefetch: 2 mt x 4 ks x 2 float4 = 64 VGPR
  if (is_xw) {
#pragma unroll
    for (int mt = 0; mt < 2; ++mt) {
      const int rowA = mq * 32 + mt * 16 + colr;
      const float* xq = x + ((size_t)rowA * Tn) * 512 + kq * 128 + kg * 8;  // t=0
#pragma unroll
      for (int ks = 0; ks < 4; ++ks) {
        xp[mt][ks][0] = *(const float4*)(xq + ks * 32);
        xp[mt][ks][1] = *(const float4*)(xq + ks * 32 + 4);
      }
    }
  }

  int* const ownline = flags + g * 32;
  int* const l0line = flags + (mq * 2) * 32;
  int* const l1line = flags + (mq * 2 + 1) * 32;

  float hown[4] = {0.f, 0.f, 0.f, 0.f};   // combiner's h slice (its mt, 16 rows)

  __syncthreads();

#pragma unroll 1
  for (int t = 0; t < Tn; ++t) {
    // ---- ordering polls (flags ARE the barrier; targets x2: two combiners) ----
    if (layer == 0) {
      if (comb0 || comb1) poll2(ownline, 2 * t, l1line, 2 * (t - 3), lane);
      else if (!inside)   poll2(ownline, 2 * t, ownline, 2 * t, lane);
    } else {
      if (inside) poll2(l0line, 2 * (t + 1), l0line, 2 * (t + 1), lane);
      else        poll2(ownline, 2 * t, ownline, 2 * t, lane);
    }
    __syncthreads();   // barrier #1: part free (combiners done reading prev step)

    f4v acc[2][3];
#pragma unroll
    for (int mt = 0; mt < 2; ++mt)
#pragma unroll
      for (int gg = 0; gg < 3; ++gg) acc[mt][gg] = (f4v){0.f, 0.f, 0.f, 0.f};

    if (is_xw) {
      // ---- x GEMM from prefetched regs; hi/lo by truncation; wl from LDS ----
#pragma unroll
      for (int ks = 0; ks < 4; ++ks) {
        s8v wl0 = wlf[(0 * 4 + ks) * 64 + lane];
        s8v wl1 = wlf[(1 * 4 + ks) * 64 + lane];
        s8v wl2 = wlf[(2 * 4 + ks) * 64 + lane];
#pragma unroll
        for (int mt = 0; mt < 2; ++mt) {
          float v[8];
          v[0] = xp[mt][ks][0].x; v[1] = xp[mt][ks][0].y;
          v[2] = xp[mt][ks][0].z; v[3] = xp[mt][ks][0].w;
          v[4] = xp[mt][ks][1].x; v[5] = xp[mt][ks][1].y;
          v[6] = xp[mt][ks][1].z; v[7] = xp[mt][ks][1].w;
          u4v au, lu;
#pragma unroll
          for (int q = 0; q < 4; ++q) {
            unsigned u0 = __float_as_uint(v[2 * q]);
            unsigned u1 = __float_as_uint(v[2 * q + 1]);
            unsigned m0 = u0 & 0xffff0000u, m1 = u1 & 0xffff0000u;
            au[q] = (u0 >> 16) | m1;
            float l0 = v[2 * q] - __uint_as_float(m0);
            float l1 = v[2 * q + 1] - __uint_as_float(m1);
            lu[q] = (__float_as_uint(l0) >> 16) | (__float_as_uint(l1) & 0xffff0000u);
          }
          s8v ah = __builtin_bit_cast(s8v, au);
          s8v al = __builtin_bit_cast(s8v, lu);
          acc[mt][0] = mfma3(ah, al, wh[0][ks], wl0, acc[mt][0]);
          acc[mt][1] = mfma3(ah, al, wh[1][ks], wl1, acc[mt][1]);
          acc[mt][2] = mfma3(ah, al, wh[2][ks], wl2, acc[mt][2]);
        }
      }
      // part write (frees acc), then issue next-step x loads
#pragma unroll
      for (int mt = 0; mt < 2; ++mt)
#pragma unroll
        for (int gg = 0; gg < 3; ++gg)
          *(f4v*)&part[wv][lane][mt * 12 + gg * 4] = acc[mt][gg];
      const int tpre = (t + 1 < Tn) ? (t + 1) : (Tn - 1);
#pragma unroll
      for (int mt = 0; mt < 2; ++mt) {
        const int rowA = mq * 32 + mt * 16 + colr;
        const float* xq = x + ((size_t)rowA * Tn + tpre) * 512 + kq * 128 + kg * 8;
#pragma unroll
        for (int ks = 0; ks < 4; ++ks) {
          xp[mt][ks][0] = *(const float4*)(xq + ks * 32);
          xp[mt][ks][1] = *(const float4*)(xq + ks * 32 + 4);
        }
      }
    } else {
      // ---- h GEMM: two SEQUENTIAL 16x8B batches (each fits the reg budget) ----
      const unsigned* src;
      if (inside)      src = h1ring + (size_t)(t & 3) * HS;        // l1: h1[t]
      else if (layer)  src = h2ring + (size_t)((t - 1) & 1) * HS;  // l1 h: h2[t-1]
      else             src = h1ring + (size_t)((t - 1) & 3) * HS;  // l0 h: h1[t-1]

      // ---- m-tile 0 ----
      {
        const int rowA = mq * 32 + colr;
        const ull* pb64 = (const ull*)(src + (size_t)rowA * 512 + kq * 128 + kg * 8);
        ull ub[16];
#pragma unroll
        for (int i = 0; i < 16; ++i)
          ub[i] = ld_mall64(pb64 + (i >> 2) * 16 + (i & 3));
#pragma unroll
        for (int ks = 0; ks < 4; ++ks) {
          s8v wl0 = wlf[(0 * 4 + ks) * 64 + lane];
          s8v wl1 = wlf[(1 * 4 + ks) * 64 + lane];
          s8v wl2 = wlf[(2 * 4 + ks) * 64 + lane];
          u4v ahw, alw;
#pragma unroll
          for (int j = 0; j < 4; ++j) {
            unsigned a = (unsigned)ub[ks * 4 + j];
            unsigned b = (unsigned)(ub[ks * 4 + j] >> 32);
            ahw[j] = (a >> 16) | (b & 0xffff0000u);
            alw[j] = (a & 0xffffu) | (b << 16);
          }
          s8v AH = __builtin_bit_cast(s8v, ahw);
          s8v AL = __builtin_bit_cast(s8v, alw);
          acc[0][0] = mfma3(AH, AL, wh[0][ks], wl0, acc[0][0]);
          acc[0][1] = mfma3(AH, AL, wh[1][ks], wl1, acc[0][1]);
          acc[0][2] = mfma3(AH, AL, wh[2][ks], wl2, acc[0][2]);
        }
      }
      asm volatile("" ::: "memory");   // keep tile-1 loads from merging into tile 0
      // ---- m-tile 1 ----
      {
        const int rowA = mq * 32 + 16 + colr;
        const ull* pb64 = (const ull*)(src + (size_t)rowA * 512 + kq * 128 + kg * 8);
        ull ub[16];
#pragma unroll
        for (int i = 0; i < 16; ++i)
          ub[i] = ld_mall64(pb64 + (i >> 2) * 16 + (i & 3));
#pragma unroll
        for (int ks = 0; ks < 4; ++ks) {
          s8v wl0 = wlf[(0 * 4 + ks) * 64 + lane];
          s8v wl1 = wlf[(1 * 4 + ks) * 64 + lane];
          s8v wl2 = wlf[(2 * 4 + ks) * 64 + lane];
          u4v ahw, alw;
#pragma unroll
          for (int j = 0; j < 4; ++j) {
            unsigned a = (unsigned)ub[ks * 4 + j];
            unsigned b = (unsigned)(ub[ks * 4 + j] >> 32);
            ahw[j] = (a >> 16) | (b & 0xffff0000u);
            alw[j] = (a & 0xffffu) | (b << 16);
          }
          s8v AH = __builtin_bit_cast(s8v, ahw);
          s8v AL = __builtin_bit_cast(s8v, alw);
          acc[1][0] = mfma3(AH, AL, wh[0][ks], wl0, acc[1][0]);
          acc[1][1] = mfma3(AH, AL, wh[1][ks], wl1, acc[1][1]);
          acc[1][2] = mfma3(AH, AL, wh[2][ks], wl2, acc[1][2]);
        }
      }
      // part write: combiners stash only their OTHER mt; others both mt
      if (comb0) {
#pragma unroll
        for (int gg = 0; gg < 3; ++gg)
          *(f4v*)&part[4][lane][gg * 4] = acc[1][gg];
      } else if (comb1) {
#pragma unroll
        for (int gg = 0; gg < 3; ++gg)
          *(f4v*)&part[5][lane][gg * 4] = acc[0][gg];
      } else {
#pragma unroll
        for (int mt = 0; mt < 2; ++mt)
#pragma unroll
          for (int gg = 0; gg < 3; ++gg)
            *(f4v*)&part[wv][lane][mt * 12 + gg * 4] = acc[mt][gg];
      }
    }
    __syncthreads();   // barrier #2: parts ready

    // ---- combiners (waves 4, 5 in parallel, one mt each) ----
    if (comb0 || comb1) {
      const int mt = comb0 ? 0 : 1;
      const int moff = mt * 12;
      f4v xs[3], hsum[3];
#pragma unroll
      for (int gg = 0; gg < 3; ++gg) {
        xs[gg] = *(const f4v*)&part[0][lane][moff + gg * 4]
               + *(const f4v*)&part[1][lane][moff + gg * 4]
               + *(const f4v*)&part[2][lane][moff + gg * 4]
               + *(const f4v*)&part[3][lane][moff + gg * 4];
        hsum[gg] = acc[mt][gg]
                 + *(const f4v*)&part[comb0 ? 5 : 4][lane][gg * 4]
                 + *(const f4v*)&part[6][lane][moff + gg * 4]
                 + *(const f4v*)&part[7][lane][moff + gg * 4];
      }
      unsigned* od = layer ? (h2ring + (size_t)(t & 1) * HS)
                           : (h1ring + (size_t)(t & 3) * HS);
#pragma unroll
      for (int r = 0; r < 4; ++r) {
        float rr = sigm(xs[0][r] + hsum[0][r] + brz);
        float zz = sigm(xs[1][r] + hsum[1][r] + bzz);
        float nn = tanh_f(xs[2][r] + bin + rr * (hsum[2][r] + bhn));
        float h = (1.f - zz) * nn + zz * hown[r];
        hown[r] = h;
        const int row = mq * 32 + mt * 16 + kg * 4 + r;
        unsigned short hi = f2bf(h);
        unsigned pk = ((unsigned)hi << 16) | (unsigned)f2bf(h - bf2f(hi));
        st_mall(od + (size_t)row * 512 + col, pk);
        if (layer == 1 && t == Tn - 1) h2fin[(size_t)row * 512 + col] = h;
      }
      // release: drain this wave's h stores, then one arrival tick (2/block/step)
      asm volatile("s_waitcnt vmcnt(0)" ::: "memory");
      if (lane == 0)
        __hip_atomic_fetch_add(ownline + jg, 1, __ATOMIC_RELAXED,
                               __HIP_MEMORY_SCOPE_AGENT);
    }
  }
}

// ---------- epilogue: out = h2_last @ Wfc^T + bfc ----------
__global__ __launch_bounds__(256) void fc_kernel(const float* __restrict__ h2,
                                                 const float* __restrict__ Wfc,
                                                 const float* __restrict__ bfc,
                                                 float* __restrict__ out) {
  int gid = blockIdx.x * 256 + threadIdx.x;  // 0..16383
  int b = gid >> 7, o = gid & 127;
  const float* hp = h2 + (size_t)b * Hn;
  const float* wp = Wfc + (size_t)o * Hn;
  float acc = bfc[o];
#pragma unroll 8
  for (int k = 0; k < Hn; k += 4) {
    float4 h = *(const float4*)(hp + k);
    float4 w = *(const float4*)(wp + k);
    acc = fmaf(h.x, w.x, acc); acc = fmaf(h.y, w.y, acc);
    acc = fmaf(h.z, w.z, acc); acc = fmaf(h.w, w.w, acc);
  }
  out[gid] = acc;
}

// ---------- epilogue: out_cate = out @ Wfcc^T + bfcc ----------
__global__ __launch_bounds__(256) void fcc_kernel(const float* __restrict__ outv,
                                                  const float* __restrict__ Wfcc,
                                                  const float* __restrict__ bfcc,
                                                  float* __restrict__ oc) {
  int gid = blockIdx.x * 256 + threadIdx.x;  // 0..49151
  int b = gid / 384, g = gid - b * 384;
  const float* op = outv + (size_t)b * 128;
  const float* wp = Wfcc + (size_t)g * 128;
  float acc = bfcc[g];
#pragma unroll 8
  for (int k = 0; k < 128; k += 4) {
    float4 o4 = *(const float4*)(op + k);
    float4 w4 = *(const float4*)(wp + k);
    acc = fmaf(o4.x, w4.x, acc); acc = fmaf(o4.y, w4.y, acc);
    acc = fmaf(o4.z, w4.z, acc); acc = fmaf(o4.w, w4.w, acc);
  }
  oc[gid] = acc;
}

extern "C" void kernel_launch(void* const* d_in, const int* in_sizes, int n_in,
                              void* d_out, int out_size, void* d_ws, size_t ws_size,
                              hipStream_t stream) {
  (void)in_sizes; (void)n_in; (void)out_size; (void)ws_size;
  const float* x    = (const float*)d_in[0];
  const float* Wih0 = (const float*)d_in[1];
  const float* Whh0 = (const float*)d_in[2];
  const float* bih0 = (const float*)d_in[3];
  const float* bhh0 = (const float*)d_in[4];
  const float* Wih1 = (const float*)d_in[5];
  const float* Whh1 = (const float*)d_in[6];
  const float* bih1 = (const float*)d_in[7];
  const float* bhh1 = (const float*)d_in[8];
  const float* Wfc  = (const float*)d_in[9];
  const float* bfc  = (const float*)d_in[10];
  const float* Wfcc = (const float*)d_in[11];
  const float* bfcc = (const float*)d_in[12];

  char* w = (char*)d_ws;
  int* flags = (int*)w;                            // [8][32] int, 1 KB
  unsigned* h1ring = (unsigned*)(w + 8192);        // 4 * 65536 u32 = 1 MB
  unsigned* h2ring = h1ring + 4 * HS;              // 2 * 65536 u32 = 512 KB
  float* h2fin = (float*)(h2ring + 2 * HS);        // 256 KB
  const size_t total = 8192 + (size_t)4 * HS * 4 + (size_t)2 * HS * 4 + (size_t)HS * 4;

  hipMemsetAsync(d_ws, 0, total, stream);

  gru_fused<<<NBLK, 512, 0, stream>>>(x, Wih0, Whh0, bih0, bhh0,
                                      Wih1, Whh1, bih1, bhh1,
                                      flags, h1ring, h2ring, h2fin);

  float* out = (float*)d_out;
  fc_kernel<<<64, 256, 0, stream>>>(h2fin, Wfc, bfc, out);
  fcc_kernel<<<192, 256, 0, stream>>>(out, Wfcc, bfcc, out + 16384);
}